// Round 1
// baseline (1274.316 us; speedup 1.0000x reference)
//
#include <hip/hip_runtime.h>

typedef short s16x8 __attribute__((ext_vector_type(8)));
typedef float f32x4 __attribute__((ext_vector_type(4)));

#define B_   128
#define A_   64
#define N_   2000
#define DIN  128
#define HID  512
#define H_   8
#define HD_  64
#define ND_  16

__device__ __forceinline__ unsigned short f2bf(float f) {
  union { float f; unsigned int u; } v; v.f = f;
  unsigned int u = v.u;
  unsigned int r = (u + 0x7fffu + ((u >> 16) & 1u)) >> 16;
  return (unsigned short)r;
}

__device__ __forceinline__ f32x4 mfma16(s16x8 a, s16x8 b, f32x4 c) {
  return __builtin_amdgcn_mfma_f32_16x16x32_bf16(a, b, c, 0, 0, 0);
}

// ---------------- converts ----------------
__global__ __launch_bounds__(256) void k_cvt(const float* __restrict__ src,
                                             unsigned short* __restrict__ dst, int n4) {
  int i = blockIdx.x * blockDim.x + threadIdx.x;
  int stride = gridDim.x * blockDim.x;
  for (; i < n4; i += stride) {
    float4 v = ((const float4*)src)[i];
    ushort4 o;
    o.x = f2bf(v.x); o.y = f2bf(v.y); o.z = f2bf(v.z); o.w = f2bf(v.w);
    ((ushort4*)dst)[i] = o;
  }
}

__global__ __launch_bounds__(256) void k_mask(const int* __restrict__ src,
                                              unsigned char* __restrict__ dst, int n4) {
  int i = blockIdx.x * blockDim.x + threadIdx.x;
  int stride = gridDim.x * blockDim.x;
  for (; i < n4; i += stride) {
    int4 v = ((const int4*)src)[i];
    uchar4 o;
    o.x = v.x ? 1 : 0; o.y = v.y ? 1 : 0; o.z = v.z ? 1 : 0; o.w = v.w ? 1 : 0;
    ((uchar4*)dst)[i] = o;
  }
}

// ---------------- fused attn1 (flash over N) ----------------
// one block per (b, head); BR=0: depot agents 0..15 on context_d, BR=1: agents 16..63 on context
template <int BR>
__global__ __launch_bounds__(256) void k_attn1(const unsigned short* __restrict__ st,
                                               const unsigned short* __restrict__ ctx,
                                               const unsigned short* __restrict__ ctxd,
                                               const unsigned short* __restrict__ wq,
                                               const unsigned short* __restrict__ wk1,
                                               const unsigned short* __restrict__ wv1,
                                               const unsigned char* __restrict__ mask,
                                               float* __restrict__ x) {
  constexpr int AT = BR ? 3 : 1;      // a-tiles of 16
  constexpr int a0 = BR ? ND_ : 0;

  __shared__ unsigned short ctx_lds[64][136];   // padded pitch: 16B-aligned rows, bank-shifted
  __shared__ unsigned short K_lds[64][72];      // K[n][d] for this head
  __shared__ unsigned short VT_lds[64][72];     // V^T[d][n]
  __shared__ unsigned short Q_lds[48][72];      // Q[a][d]
  __shared__ unsigned short P_lds[48][72];      // P[a][n]
  __shared__ float red_max[4][48];
  __shared__ float red_sum[4][48];

  const int tid = threadIdx.x;
  const int w = tid >> 6;        // wave 0..3
  const int lane = tid & 63;
  const int rn = lane & 15;
  const int kq = lane >> 4;      // 0..3

  const int bid = blockIdx.x;
  const int b = bid >> 3;
  const int h = bid & 7;
  const unsigned short* __restrict__ C = BR ? ctx : ctxd;

  // per-wave weight fragments for K/V projection: wave w owns head-dim slice [w*16, w*16+16)
  s16x8 kfrag[4], vfrag[4];
  {
    const size_t orow = (size_t)(h * HD_ + w * 16 + rn) * DIN;
#pragma unroll
    for (int k = 0; k < 4; ++k) {
      kfrag[k] = *(const s16x8*)(wk1 + orow + k * 32 + kq * 8);
      vfrag[k] = *(const s16x8*)(wv1 + orow + k * 32 + kq * 8);
    }
  }

  // Q projection (once): wave w computes d-slice w
  {
    s16x8 qw[4];
#pragma unroll
    for (int k = 0; k < 4; ++k)
      qw[k] = *(const s16x8*)(wq + (size_t)(h * HD_ + w * 16 + rn) * DIN + k * 32 + kq * 8);
#pragma unroll
    for (int at = 0; at < AT; ++at) {
      f32x4 acc = {0.f, 0.f, 0.f, 0.f};
#pragma unroll
      for (int k = 0; k < 4; ++k) {
        s16x8 af = *(const s16x8*)(st + (size_t)(b * A_ + a0 + at * 16 + rn) * DIN + k * 32 + kq * 8);
        acc = mfma16(af, qw[k], acc);
      }
#pragma unroll
      for (int r = 0; r < 4; ++r)
        Q_lds[at * 16 + kq * 4 + r][w * 16 + rn] = f2bf(acc[r]);
    }
  }
  __syncthreads();

  f32x4 O[AT];
  float m_run[AT][4], l_run[AT][4];
#pragma unroll
  for (int at = 0; at < AT; ++at) {
    O[at] = {0.f, 0.f, 0.f, 0.f};
#pragma unroll
    for (int r = 0; r < 4; ++r) { m_run[at][r] = -1e30f; l_run[at][r] = 0.f; }
  }

  const int NT = (N_ + 63) / 64;   // 32
  for (int nt = 0; nt < NT; ++nt) {
    const int n0 = nt * 64;
    // stage ctx tile (64 x 128 bf16)
#pragma unroll
    for (int i = 0; i < 4; ++i) {
      int c = tid + i * 256;          // 0..1023
      int row = c >> 4;               // 0..63
      int col = (c & 15) * 8;
      s16x8 v = {0, 0, 0, 0, 0, 0, 0, 0};
      if (n0 + row < N_)
        v = *(const s16x8*)(C + ((size_t)b * N_ + n0 + row) * DIN + col);
      *(s16x8*)&ctx_lds[row][col] = v;
    }
    __syncthreads();   // B1

    // project K,V: wave w -> d-slice w, all 4 n-subtiles
    for (int ns = 0; ns < 4; ++ns) {
      s16x8 af[4];
#pragma unroll
      for (int k = 0; k < 4; ++k)
        af[k] = *(const s16x8*)&ctx_lds[ns * 16 + rn][k * 32 + kq * 8];
      f32x4 aK = {0.f, 0.f, 0.f, 0.f}, aV = {0.f, 0.f, 0.f, 0.f};
#pragma unroll
      for (int k = 0; k < 4; ++k) {
        aK = mfma16(af[k], kfrag[k], aK);
        aV = mfma16(af[k], vfrag[k], aV);
      }
#pragma unroll
      for (int r = 0; r < 4; ++r) {
        K_lds[ns * 16 + kq * 4 + r][w * 16 + rn] = f2bf(aK[r]);
        VT_lds[w * 16 + rn][ns * 16 + kq * 4 + r] = f2bf(aV[r]);
      }
    }
    __syncthreads();   // B2

    // QK^T for n-subtile w  (lane column n = n0 + w*16 + rn, rows a = at*16+kq*4+r)
    float lg[AT][4];
    float scale_[AT][4];
#pragma unroll
    for (int at = 0; at < AT; ++at) {
      f32x4 acc = {0.f, 0.f, 0.f, 0.f};
#pragma unroll
      for (int kd = 0; kd < 2; ++kd) {
        s16x8 qa = *(const s16x8*)&Q_lds[at * 16 + rn][kd * 32 + kq * 8];
        s16x8 kb = *(const s16x8*)&K_lds[w * 16 + rn][kd * 32 + kq * 8];
        acc = mfma16(qa, kb, acc);
      }
      const int ng = n0 + w * 16 + rn;
      const bool nvalid = ng < N_;
#pragma unroll
      for (int r = 0; r < 4; ++r) {
        float v;
        if (!nvalid) v = -3.0e38f;
        else {
          v = acc[r] * 0.125f;   // 1/sqrt(64)
          int a = a0 + at * 16 + kq * 4 + r;
          if (mask[((size_t)b * A_ + a) * N_ + ng]) v = -1e4f;
        }
        lg[at][r] = v;
      }
      float vm[4];
#pragma unroll
      for (int r = 0; r < 4; ++r) vm[r] = lg[at][r];
#pragma unroll
      for (int off = 1; off < 16; off <<= 1)
#pragma unroll
        for (int r = 0; r < 4; ++r) vm[r] = fmaxf(vm[r], __shfl_xor(vm[r], off));
      if (rn == 0) {
#pragma unroll
        for (int r = 0; r < 4; ++r) red_max[w][at * 16 + kq * 4 + r] = vm[r];
      }
    }
    __syncthreads();   // B3

#pragma unroll
    for (int at = 0; at < AT; ++at) {
#pragma unroll
      for (int r = 0; r < 4; ++r) {
        int a = at * 16 + kq * 4 + r;
        float tm = fmaxf(fmaxf(red_max[0][a], red_max[1][a]), fmaxf(red_max[2][a], red_max[3][a]));
        float mn = fmaxf(m_run[at][r], tm);
        scale_[at][r] = __expf(m_run[at][r] - mn);
        m_run[at][r] = mn;
        float p = __expf(lg[at][r] - mn);
        lg[at][r] = p;
        P_lds[a][w * 16 + rn] = f2bf(p);
      }
      float vs[4];
#pragma unroll
      for (int r = 0; r < 4; ++r) vs[r] = lg[at][r];
#pragma unroll
      for (int off = 1; off < 16; off <<= 1)
#pragma unroll
        for (int r = 0; r < 4; ++r) vs[r] += __shfl_xor(vs[r], off);
      if (rn == 0) {
#pragma unroll
        for (int r = 0; r < 4; ++r) red_sum[w][at * 16 + kq * 4 + r] = vs[r];
      }
    }
    __syncthreads();   // B4

    // PV: wave w -> d-slice w
#pragma unroll
    for (int at = 0; at < AT; ++at) {
      f32x4 acc = O[at];
#pragma unroll
      for (int r = 0; r < 4; ++r) acc[r] *= scale_[at][r];
#pragma unroll
      for (int kn = 0; kn < 2; ++kn) {
        s16x8 pa = *(const s16x8*)&P_lds[at * 16 + rn][kn * 32 + kq * 8];
        s16x8 vb = *(const s16x8*)&VT_lds[w * 16 + rn][kn * 32 + kq * 8];
        acc = mfma16(pa, vb, acc);
      }
      O[at] = acc;
#pragma unroll
      for (int r = 0; r < 4; ++r) {
        int a = at * 16 + kq * 4 + r;
        l_run[at][r] = l_run[at][r] * scale_[at][r] +
                       red_sum[0][a] + red_sum[1][a] + red_sum[2][a] + red_sum[3][a];
      }
    }
  }

  // epilogue: write x with the faithful (b,H,a,hd)->(b,a,hid) reshape scramble
#pragma unroll
  for (int at = 0; at < AT; ++at) {
#pragma unroll
    for (int r = 0; r < 4; ++r) {
      int a_idx = at * 16 + kq * 4 + r;
      int d = w * 16 + rn;
      float val = O[at][r] / l_run[at][r];
      int row = BR ? (ND_ + h * 6 + (a_idx >> 3)) : (h * 2 + (a_idx >> 3));
      int col = (a_idx & 7) * HD_ + d;
      x[((size_t)b * A_ + row) * HID + col] = val;
    }
  }
}

// ---------------- fc GEMM: x2 = x @ w_fc^T ----------------
__global__ __launch_bounds__(256) void k_fc(const float* __restrict__ x,
                                            const unsigned short* __restrict__ wfc,
                                            unsigned short* __restrict__ x2) {
  const int tid = threadIdx.x;
  const int w = tid >> 6;
  const int lane = tid & 63;
  const int rn = lane & 15, kq = lane >> 4;
  const size_t rowbase = (size_t)blockIdx.x * 16;

  f32x4 acc[8];
#pragma unroll
  for (int ot = 0; ot < 8; ++ot) acc[ot] = {0.f, 0.f, 0.f, 0.f};

  for (int k = 0; k < 16; ++k) {
    const float* ap = x + (rowbase + rn) * HID + k * 32 + kq * 8;
    float4 a1 = *(const float4*)ap;
    float4 a2 = *(const float4*)(ap + 4);
    s16x8 af;
    af[0] = (short)f2bf(a1.x); af[1] = (short)f2bf(a1.y);
    af[2] = (short)f2bf(a1.z); af[3] = (short)f2bf(a1.w);
    af[4] = (short)f2bf(a2.x); af[5] = (short)f2bf(a2.y);
    af[6] = (short)f2bf(a2.z); af[7] = (short)f2bf(a2.w);
#pragma unroll
    for (int ot = 0; ot < 8; ++ot) {
      s16x8 bf = *(const s16x8*)(wfc + (size_t)(w * 128 + ot * 16 + rn) * HID + k * 32 + kq * 8);
      acc[ot] = mfma16(af, bf, acc[ot]);
    }
  }
#pragma unroll
  for (int ot = 0; ot < 8; ++ot)
#pragma unroll
    for (int r = 0; r < 4; ++r)
      x2[(rowbase + kq * 4 + r) * HID + w * 128 + ot * 16 + rn] = f2bf(acc[ot][r]);
}

// ---------------- fused K2 projection + final logits ----------------
__global__ __launch_bounds__(256) void k_logits(const unsigned short* __restrict__ ctx,
                                                const unsigned short* __restrict__ ctxd,
                                                const unsigned short* __restrict__ wk2,
                                                const unsigned short* __restrict__ x2,
                                                float* __restrict__ out) {
  __shared__ unsigned short ctx_lds[32][136];
  __shared__ unsigned short K2_lds[32][520];

  const int tid = threadIdx.x;
  const int w = tid >> 6;
  const int lane = tid & 63;
  const int rn = lane & 15, kq = lane >> 4;
  const int nt = blockIdx.x;        // 0..62
  const int branch = blockIdx.y;    // 0 depot / 1 rest
  const int b = blockIdx.z;
  const int n0 = nt * 32;
  const unsigned short* __restrict__ C = branch ? ctx : ctxd;
  const int rowbase = branch ? ND_ : 0;
  const int RT = branch ? 3 : 1;

  // stage ctx tile (32 x 128)
#pragma unroll
  for (int i = 0; i < 2; ++i) {
    int c = tid + i * 256;        // 0..511
    int row = c >> 4;             // 0..31
    int col = (c & 15) * 8;
    s16x8 v = {0, 0, 0, 0, 0, 0, 0, 0};
    if (n0 + row < N_)
      v = *(const s16x8*)(C + ((size_t)b * N_ + n0 + row) * DIN + col);
    *(s16x8*)&ctx_lds[row][col] = v;
  }
  __syncthreads();

  // project K2: wave w covers output cols [w*128, w*128+128)
  {
    s16x8 af[2][4];
#pragma unroll
    for (int ni = 0; ni < 2; ++ni)
#pragma unroll
      for (int k = 0; k < 4; ++k)
        af[ni][k] = *(const s16x8*)&ctx_lds[ni * 16 + rn][k * 32 + kq * 8];
    for (int ot = 0; ot < 8; ++ot) {
      s16x8 bfr[4];
#pragma unroll
      for (int k = 0; k < 4; ++k)
        bfr[k] = *(const s16x8*)(wk2 + (size_t)(w * 128 + ot * 16 + rn) * DIN + k * 32 + kq * 8);
#pragma unroll
      for (int ni = 0; ni < 2; ++ni) {
        f32x4 acc = {0.f, 0.f, 0.f, 0.f};
#pragma unroll
        for (int k = 0; k < 4; ++k) acc = mfma16(af[ni][k], bfr[k], acc);
#pragma unroll
        for (int r = 0; r < 4; ++r)
          K2_lds[ni * 16 + kq * 4 + r][w * 128 + ot * 16 + rn] = f2bf(acc[r]);
      }
    }
  }
  __syncthreads();

  const float norm2 = 0.04419417382415922f;  // 1/sqrt(512)
  for (int j = w; j < RT * 2; j += 4) {
    int rt = j >> 1, ns = j & 1;
    f32x4 acc = {0.f, 0.f, 0.f, 0.f};
    for (int k = 0; k < 16; ++k) {
      s16x8 af = *(const s16x8*)(x2 + (size_t)(b * A_ + rowbase + rt * 16 + rn) * HID + k * 32 + kq * 8);
      s16x8 bf = *(const s16x8*)&K2_lds[ns * 16 + rn][k * 32 + kq * 8];
      acc = mfma16(af, bf, acc);
    }
    int ng = n0 + ns * 16 + rn;
    if (ng < N_) {
#pragma unroll
      for (int r = 0; r < 4; ++r) {
        int row = rowbase + rt * 16 + kq * 4 + r;
        out[((size_t)b * A_ + row) * N_ + ng] = acc[r] * norm2;
      }
    }
  }
}

// ---------------- row softmax (mask + /T applied here) ----------------
__global__ __launch_bounds__(256) void k_softmax(float* __restrict__ out,
                                                 const unsigned char* __restrict__ mask,
                                                 const int* __restrict__ Tptr) {
  __shared__ float z[N_];
  __shared__ float red[4];
  const size_t row = blockIdx.x;
  const int tid = threadIdx.x;
  const float Tinv = 1.0f / (float)Tptr[0];

  float lmax = -3.0e38f;
  for (int i = tid; i < N_; i += 256) {
    float v = out[row * N_ + i];
    if (mask[row * N_ + i]) v = -1e4f;
    v *= Tinv;
    z[i] = v;
    lmax = fmaxf(lmax, v);
  }
#pragma unroll
  for (int off = 1; off < 64; off <<= 1) lmax = fmaxf(lmax, __shfl_xor(lmax, off));
  if ((tid & 63) == 0) red[tid >> 6] = lmax;
  __syncthreads();
  float gmax = fmaxf(fmaxf(red[0], red[1]), fmaxf(red[2], red[3]));

  float lsum = 0.f;
  for (int i = tid; i < N_; i += 256) {
    float e = __expf(z[i] - gmax);
    z[i] = e;
    lsum += e;
  }
#pragma unroll
  for (int off = 1; off < 64; off <<= 1) lsum += __shfl_xor(lsum, off);
  __syncthreads();
  if ((tid & 63) == 0) red[tid >> 6] = lsum;
  __syncthreads();
  float inv = 1.0f / (red[0] + red[1] + red[2] + red[3]);
  for (int i = tid; i < N_; i += 256) out[row * N_ + i] = z[i] * inv;
}

// ---------------- launch ----------------
extern "C" void kernel_launch(void* const* d_in, const int* in_sizes, int n_in,
                              void* d_out, int out_size, void* d_ws, size_t ws_size,
                              hipStream_t stream) {
  const float* state_t   = (const float*)d_in[0];
  const float* context   = (const float*)d_in[1];
  const float* context_d = (const float*)d_in[2];
  const float* w_q  = (const float*)d_in[3];
  const float* w_k1 = (const float*)d_in[4];
  const float* w_v1 = (const float*)d_in[5];
  const float* w_fc = (const float*)d_in[6];
  const float* w_k2 = (const float*)d_in[7];
  const int* maski  = (const int*)d_in[9];
  const int* Tptr   = (const int*)d_in[10];
  float* out = (float*)d_out;

  char* ws = (char*)d_ws;
  unsigned short* ctxb  = (unsigned short*)ws; ws += (size_t)B_ * N_ * DIN * 2;
  unsigned short* ctxdb = (unsigned short*)ws; ws += (size_t)B_ * N_ * DIN * 2;
  unsigned short* stb   = (unsigned short*)ws; ws += (size_t)B_ * A_ * DIN * 2;
  unsigned short* wqb   = (unsigned short*)ws; ws += (size_t)HID * DIN * 2;
  unsigned short* wk1b  = (unsigned short*)ws; ws += (size_t)HID * DIN * 2;
  unsigned short* wv1b  = (unsigned short*)ws; ws += (size_t)HID * DIN * 2;
  unsigned short* wk2b  = (unsigned short*)ws; ws += (size_t)HID * DIN * 2;
  unsigned short* wfcb  = (unsigned short*)ws; ws += (size_t)HID * HID * 2;
  unsigned char*  mask8 = (unsigned char*)ws;  ws += (size_t)B_ * A_ * N_;
  float*          x     = (float*)ws;          ws += (size_t)B_ * A_ * HID * 4;
  unsigned short* x2    = (unsigned short*)ws; ws += (size_t)B_ * A_ * HID * 2;

  k_cvt<<<2048, 256, 0, stream>>>(context,   ctxb,  B_ * N_ * DIN / 4);
  k_cvt<<<2048, 256, 0, stream>>>(context_d, ctxdb, B_ * N_ * DIN / 4);
  k_cvt<<<256,  256, 0, stream>>>(state_t,   stb,   B_ * A_ * DIN / 4);
  k_cvt<<<64,   256, 0, stream>>>(w_q,  wqb,  HID * DIN / 4);
  k_cvt<<<64,   256, 0, stream>>>(w_k1, wk1b, HID * DIN / 4);
  k_cvt<<<64,   256, 0, stream>>>(w_v1, wv1b, HID * DIN / 4);
  k_cvt<<<64,   256, 0, stream>>>(w_k2, wk2b, HID * DIN / 4);
  k_cvt<<<256,  256, 0, stream>>>(w_fc, wfcb, HID * HID / 4);
  k_mask<<<2048, 256, 0, stream>>>(maski, mask8, B_ * A_ * N_ / 4);

  k_attn1<0><<<B_ * 8, 256, 0, stream>>>(stb, ctxb, ctxdb, wqb, wk1b, wv1b, mask8, x);
  k_attn1<1><<<B_ * 8, 256, 0, stream>>>(stb, ctxb, ctxdb, wqb, wk1b, wv1b, mask8, x);

  k_fc<<<(B_ * A_) / 16, 256, 0, stream>>>(x, wfcb, x2);

  dim3 g3((N_ + 31) / 32, 2, B_);
  k_logits<<<g3, 256, 0, stream>>>(ctxb, ctxdb, wk2b, x2, out);

  k_softmax<<<B_ * A_, 256, 0, stream>>>(out, mask8, Tptr);
}

// Round 2
// 784.697 us; speedup vs baseline: 1.6240x; 1.6240x over previous
//
#include <hip/hip_runtime.h>

typedef short s16x8 __attribute__((ext_vector_type(8)));
typedef float f32x4 __attribute__((ext_vector_type(4)));

#define B_   128
#define A_   64
#define N_   2000
#define DIN  128
#define HID  512
#define H_   8
#define HD_  64
#define ND_  16
#define NT_  32

__device__ __forceinline__ unsigned short f2bf(float f) {
  union { float f; unsigned int u; } v; v.f = f;
  unsigned int u = v.u;
  unsigned int r = (u + 0x7fffu + ((u >> 16) & 1u)) >> 16;
  return (unsigned short)r;
}

__device__ __forceinline__ f32x4 mfma16(s16x8 a, s16x8 b, f32x4 c) {
  return __builtin_amdgcn_mfma_f32_16x16x32_bf16(a, b, c, 0, 0, 0);
}

__device__ __forceinline__ unsigned int cvtpk(float lo, float hi) {
  unsigned int r;
  asm("v_cvt_pk_bf16_f32 %0, %1, %2" : "=v"(r) : "v"(lo), "v"(hi));
  return r;
}

__device__ __forceinline__ void gload16(const void* g, void* l) {
  __builtin_amdgcn_global_load_lds(
      (const __attribute__((address_space(1))) unsigned int*)g,
      (__attribute__((address_space(3))) unsigned int*)l, 16, 0, 0);
}

__device__ __forceinline__ void barrier_lds() {
  asm volatile("s_waitcnt lgkmcnt(0)" ::: "memory");
  __builtin_amdgcn_s_barrier();
  __builtin_amdgcn_sched_barrier(0);
}
__device__ __forceinline__ void barrier_full() {
  asm volatile("s_waitcnt vmcnt(0) lgkmcnt(0)" ::: "memory");
  __builtin_amdgcn_s_barrier();
  __builtin_amdgcn_sched_barrier(0);
}

// ---------------- converts ----------------
__global__ __launch_bounds__(256) void k_cvt(const float* __restrict__ src,
                                             unsigned short* __restrict__ dst, int n4) {
  int i = blockIdx.x * blockDim.x + threadIdx.x;
  int stride = gridDim.x * blockDim.x;
  for (; i < n4; i += stride) {
    float4 v = ((const float4*)src)[i];
    ushort4 o;
    o.x = f2bf(v.x); o.y = f2bf(v.y); o.z = f2bf(v.z); o.w = f2bf(v.w);
    ((ushort4*)dst)[i] = o;
  }
}

__global__ __launch_bounds__(256) void k_mask(const int* __restrict__ src,
                                              unsigned char* __restrict__ dst, int n4) {
  int i = blockIdx.x * blockDim.x + threadIdx.x;
  int stride = gridDim.x * blockDim.x;
  for (; i < n4; i += stride) {
    int4 v = ((const int4*)src)[i];
    uchar4 o;
    o.x = v.x ? 1 : 0; o.y = v.y ? 1 : 0; o.z = v.z ? 1 : 0; o.w = v.w ? 1 : 0;
    ((uchar4*)dst)[i] = o;
  }
}

// ---------------- fused attn1 (flash over N, fixed-max softmax) ----------------
template <int BR>
__device__ __forceinline__ void attn_body(
    int sub,
    const unsigned short* __restrict__ st, const unsigned short* __restrict__ C,
    const unsigned short* __restrict__ wq, const unsigned short* __restrict__ wk1,
    const unsigned short* __restrict__ wv1, const unsigned char* __restrict__ mask,
    float* __restrict__ x,
    unsigned short (*ctx_lds)[128], unsigned short (*K_lds)[72],
    unsigned short (*VT_lds)[72], unsigned short (*QP_lds)[72], float (*red_l)[48]) {
  constexpr int AT = BR ? 3 : 1;
  constexpr int a0 = BR ? ND_ : 0;
  const int tid = threadIdx.x;
  const int w = tid >> 6, lane = tid & 63, rn = lane & 15, kq = lane >> 4;
  const int b = sub >> 3, h = sub & 7;
  const int srow = lane >> 4;      // 0..3 rows within a 4-row staging stripe
  const int scol = lane & 15;      // 16B-block column 0..15

  // ---- stage tile 0 (global source pre-swizzled; LDS linear)
#pragma unroll
  for (int i = 0; i < 4; ++i) {
    int r0 = i * 16 + w * 4;
    int row = r0 + srow;
    const char* g = (const char*)C + (((size_t)b * N_ + row) << 8) + ((scol ^ (row & 7)) << 4);
    gload16(g, (char*)&ctx_lds[0][0] + (r0 << 8));
  }

  // ---- per-wave weight fragments (rows o = h*64 + w*16 + rn)
  s16x8 kfrag[4], vfrag[4];
  {
    const size_t orow = (size_t)(h * HD_ + w * 16 + rn) * DIN;
#pragma unroll
    for (int k = 0; k < 4; ++k) {
      kfrag[k] = *(const s16x8*)(wk1 + orow + k * 32 + kq * 8);
      vfrag[k] = *(const s16x8*)(wv1 + orow + k * 32 + kq * 8);
    }
  }

  // ---- Q projection -> QP_lds[a][d]  (D[o][a]: lane holds 4 o at fixed a=rn)
  {
    s16x8 qw[4];
    const size_t orow = (size_t)(h * HD_ + w * 16 + rn) * DIN;
#pragma unroll
    for (int k = 0; k < 4; ++k) qw[k] = *(const s16x8*)(wq + orow + k * 32 + kq * 8);
#pragma unroll
    for (int at = 0; at < AT; ++at) {
      f32x4 acc = {0.f, 0.f, 0.f, 0.f};
#pragma unroll
      for (int k = 0; k < 4; ++k) {
        s16x8 sf = *(const s16x8*)(st + (size_t)(b * A_ + a0 + at * 16 + rn) * DIN + k * 32 + kq * 8);
        acc = mfma16(qw[k], sf, acc);
      }
      uint2 pk; pk.x = cvtpk(acc[0], acc[1]); pk.y = cvtpk(acc[2], acc[3]);
      *(uint2*)&QP_lds[at * 16 + rn][w * 16 + kq * 4] = pk;
    }
  }
  barrier_lds();

  // Q B-frags to registers (row a = rn, k-octet via kq)
  s16x8 qf[AT][2];
#pragma unroll
  for (int at = 0; at < AT; ++at)
#pragma unroll
    for (int kd = 0; kd < 2; ++kd)
      qf[at][kd] = *(const s16x8*)&QP_lds[at * 16 + rn][kd * 32 + kq * 8];

  f32x4 O[AT];
  float lpart[AT];
#pragma unroll
  for (int at = 0; at < AT; ++at) { O[at] = {0.f, 0.f, 0.f, 0.f}; lpart[at] = 0.f; }

  for (int nt = 0; nt < NT_; ++nt) {
    const int n0 = nt * 64;
    barrier_full();   // tile nt staged; all prev-tile LDS readers done

    // mask loads (issued first => oldest vmem; QK can wait them with gloads in flight)
    unsigned int m4[AT];
    const int ngbase = n0 + w * 16 + kq * 4;
    const int ngc = ngbase > (N_ - 4) ? (N_ - 4) : ngbase;
#pragma unroll
    for (int at = 0; at < AT; ++at)
      m4[at] = *(const unsigned int*)(mask + (size_t)(b * A_ + a0 + at * 16 + rn) * N_ + ngc);

    // ---- proj K,V for the 4 n-subtiles (wave w owns d-slice w)
#pragma unroll
    for (int ns = 0; ns < 4; ++ns) {
      s16x8 cf[4];
#pragma unroll
      for (int kd = 0; kd < 4; ++kd)
        cf[kd] = *(const s16x8*)&ctx_lds[ns * 16 + rn][(((kd << 2) | kq) ^ (rn & 7)) << 3];
      f32x4 aK = {0.f, 0.f, 0.f, 0.f}, aV = {0.f, 0.f, 0.f, 0.f};
#pragma unroll
      for (int kd = 0; kd < 4; ++kd) {
        aK = mfma16(kfrag[kd], cf[kd], aK);   // D[o][n]: lane n=rn, 4 o's
        aV = mfma16(cf[kd], vfrag[kd], aV);   // D[n][o]: lane o=rn, 4 n's
      }
      if (n0 + 64 > N_) {
#pragma unroll
        for (int r = 0; r < 4; ++r)
          if (n0 + ns * 16 + kq * 4 + r >= N_) aV[r] = 0.f;  // keep PV free of Inf*0
      }
      uint2 pkK; pkK.x = cvtpk(aK[0], aK[1]); pkK.y = cvtpk(aK[2], aK[3]);
      *(uint2*)&K_lds[ns * 16 + rn][w * 16 + kq * 4] = pkK;
      uint2 pkV; pkV.x = cvtpk(aV[0], aV[1]); pkV.y = cvtpk(aV[2], aV[3]);
      *(uint2*)&VT_lds[w * 16 + rn][ns * 16 + kq * 4] = pkV;
    }
    barrier_lds();    // K/VT ready, ctx_lds free

    // ---- async prefetch tile nt+1
    if (nt + 1 < NT_) {
      const int n1 = n0 + 64;
#pragma unroll
      for (int i = 0; i < 4; ++i) {
        int r0 = i * 16 + w * 4;
        int row = r0 + srow;
        const char* g = (const char*)C + (((size_t)b * N_ + n1 + row) << 8) + ((scol ^ (row & 7)) << 4);
        gload16(g, (char*)&ctx_lds[0][0] + (r0 << 8));
      }
    }

    // ---- QK^T (swapped: D[n][a], lane holds 4 consecutive n at a=at*16+rn)
    s16x8 kf[2];
#pragma unroll
    for (int kd = 0; kd < 2; ++kd)
      kf[kd] = *(const s16x8*)&K_lds[w * 16 + rn][kd * 32 + kq * 8];
#pragma unroll
    for (int at = 0; at < AT; ++at) {
      f32x4 acc = {0.f, 0.f, 0.f, 0.f};
#pragma unroll
      for (int kd = 0; kd < 2; ++kd) acc = mfma16(kf[kd], qf[at][kd], acc);
      float p[4];
#pragma unroll
      for (int r = 0; r < 4; ++r) {
        bool valid = (ngbase + r < N_) && (((m4[at] >> (8 * r)) & 255u) == 0u);
        float e = valid ? acc[r] * 0.125f - 8.0f : -1.0e4f;  // fixed-max softmax
        p[r] = __expf(e);
      }
      lpart[at] += (p[0] + p[1]) + (p[2] + p[3]);
      uint2 pkP; pkP.x = cvtpk(p[0], p[1]); pkP.y = cvtpk(p[2], p[3]);
      *(uint2*)&QP_lds[at * 16 + rn][w * 16 + kq * 4] = pkP;  // P[a][n]
    }
    barrier_lds();    // P ready

    // ---- PV (wave w owns d-slice w; k = n over the 64-tile)
    s16x8 vtf[2];
#pragma unroll
    for (int kn = 0; kn < 2; ++kn)
      vtf[kn] = *(const s16x8*)&VT_lds[w * 16 + rn][kn * 32 + kq * 8];
#pragma unroll
    for (int at = 0; at < AT; ++at) {
      f32x4 acc = O[at];
#pragma unroll
      for (int kn = 0; kn < 2; ++kn)
        acc = mfma16(*(const s16x8*)&QP_lds[at * 16 + rn][kn * 32 + kq * 8], vtf[kn], acc);
      O[at] = acc;
    }
  }

  // ---- epilogue: reduce l over kq-groups and waves, then write x
#pragma unroll
  for (int at = 0; at < AT; ++at) {
    float lp = lpart[at];
    lp += __shfl_xor(lp, 16);
    lp += __shfl_xor(lp, 32);
    if (kq == 0) red_l[w][at * 16 + rn] = lp;
  }
  barrier_lds();
#pragma unroll
  for (int at = 0; at < AT; ++at) {
#pragma unroll
    for (int r = 0; r < 4; ++r) {
      int a = at * 16 + kq * 4 + r;
      float ls = (red_l[0][a] + red_l[1][a]) + (red_l[2][a] + red_l[3][a]);
      float val = O[at][r] / ls;
      int row = BR ? (ND_ + h * 6 + (a >> 3)) : (h * 2 + (a >> 3));
      int col = (a & 7) * HD_ + w * 16 + rn;
      x[((size_t)b * A_ + row) * HID + col] = val;
    }
  }
}

__global__ __launch_bounds__(256) void k_attn1(const unsigned short* __restrict__ st,
                                               const unsigned short* __restrict__ ctx,
                                               const unsigned short* __restrict__ ctxd,
                                               const unsigned short* __restrict__ wq,
                                               const unsigned short* __restrict__ wk1,
                                               const unsigned short* __restrict__ wv1,
                                               const unsigned char* __restrict__ mask,
                                               float* __restrict__ x) {
  __shared__ unsigned short ctx_lds[64][128];
  __shared__ unsigned short K_lds[64][72];
  __shared__ unsigned short VT_lds[64][72];
  __shared__ unsigned short QP_lds[48][72];
  __shared__ float red_l[4][48];
  const int bid = blockIdx.x;
  const int sub = bid >> 1;
  if (bid & 1)
    attn_body<1>(sub, st, ctx, wq, wk1, wv1, mask, x, ctx_lds, K_lds, VT_lds, QP_lds, red_l);
  else
    attn_body<0>(sub, st, ctxd, wq, wk1, wv1, mask, x, ctx_lds, K_lds, VT_lds, QP_lds, red_l);
}

// ---------------- fc GEMM: x2 = x @ w_fc^T ----------------
__global__ __launch_bounds__(256) void k_fc(const float* __restrict__ x,
                                            const unsigned short* __restrict__ wfc,
                                            unsigned short* __restrict__ x2) {
  const int tid = threadIdx.x;
  const int w = tid >> 6;
  const int lane = tid & 63;
  const int rn = lane & 15, kq = lane >> 4;
  const size_t rowbase = (size_t)blockIdx.x * 16;

  f32x4 acc[8];
#pragma unroll
  for (int ot = 0; ot < 8; ++ot) acc[ot] = {0.f, 0.f, 0.f, 0.f};

  for (int k = 0; k < 16; ++k) {
    const float* ap = x + (rowbase + rn) * HID + k * 32 + kq * 8;
    float4 a1 = *(const float4*)ap;
    float4 a2 = *(const float4*)(ap + 4);
    s16x8 af;
    af[0] = (short)f2bf(a1.x); af[1] = (short)f2bf(a1.y);
    af[2] = (short)f2bf(a1.z); af[3] = (short)f2bf(a1.w);
    af[4] = (short)f2bf(a2.x); af[5] = (short)f2bf(a2.y);
    af[6] = (short)f2bf(a2.z); af[7] = (short)f2bf(a2.w);
#pragma unroll
    for (int ot = 0; ot < 8; ++ot) {
      s16x8 bf = *(const s16x8*)(wfc + (size_t)(w * 128 + ot * 16 + rn) * HID + k * 32 + kq * 8);
      acc[ot] = mfma16(af, bf, acc[ot]);
    }
  }
#pragma unroll
  for (int ot = 0; ot < 8; ++ot)
#pragma unroll
    for (int r = 0; r < 4; ++r)
      x2[(rowbase + kq * 4 + r) * HID + w * 128 + ot * 16 + rn] = f2bf(acc[ot][r]);
}

// ---------------- fused K2 projection + final logits ----------------
__global__ __launch_bounds__(256) void k_logits(const unsigned short* __restrict__ ctx,
                                                const unsigned short* __restrict__ ctxd,
                                                const unsigned short* __restrict__ wk2,
                                                const unsigned short* __restrict__ x2,
                                                float* __restrict__ out) {
  __shared__ unsigned short ctx_lds[32][136];
  __shared__ unsigned short K2_lds[32][520];

  const int tid = threadIdx.x;
  const int w = tid >> 6;
  const int lane = tid & 63;
  const int rn = lane & 15, kq = lane >> 4;
  const int nt = blockIdx.x;
  const int branch = blockIdx.y;
  const int b = blockIdx.z;
  const int n0 = nt * 32;
  const unsigned short* __restrict__ C = branch ? ctx : ctxd;
  const int rowbase = branch ? ND_ : 0;
  const int RT = branch ? 3 : 1;

#pragma unroll
  for (int i = 0; i < 2; ++i) {
    int c = tid + i * 256;
    int row = c >> 4;
    int col = (c & 15) * 8;
    s16x8 v = {0, 0, 0, 0, 0, 0, 0, 0};
    if (n0 + row < N_)
      v = *(const s16x8*)(C + ((size_t)b * N_ + n0 + row) * DIN + col);
    *(s16x8*)&ctx_lds[row][col] = v;
  }
  __syncthreads();

  {
    s16x8 af[2][4];
#pragma unroll
    for (int ni = 0; ni < 2; ++ni)
#pragma unroll
      for (int k = 0; k < 4; ++k)
        af[ni][k] = *(const s16x8*)&ctx_lds[ni * 16 + rn][k * 32 + kq * 8];
    for (int ot = 0; ot < 8; ++ot) {
      s16x8 bfr[4];
#pragma unroll
      for (int k = 0; k < 4; ++k)
        bfr[k] = *(const s16x8*)(wk2 + (size_t)(w * 128 + ot * 16 + rn) * DIN + k * 32 + kq * 8);
#pragma unroll
      for (int ni = 0; ni < 2; ++ni) {
        f32x4 acc = {0.f, 0.f, 0.f, 0.f};
#pragma unroll
        for (int k = 0; k < 4; ++k) acc = mfma16(af[ni][k], bfr[k], acc);
#pragma unroll
        for (int r = 0; r < 4; ++r)
          K2_lds[ni * 16 + kq * 4 + r][w * 128 + ot * 16 + rn] = f2bf(acc[r]);
      }
    }
  }
  __syncthreads();

  const float norm2 = 0.04419417382415922f;
  for (int j = w; j < RT * 2; j += 4) {
    int rt = j >> 1, ns = j & 1;
    f32x4 acc = {0.f, 0.f, 0.f, 0.f};
    for (int k = 0; k < 16; ++k) {
      s16x8 af = *(const s16x8*)(x2 + (size_t)(b * A_ + rowbase + rt * 16 + rn) * HID + k * 32 + kq * 8);
      s16x8 bf = *(const s16x8*)&K2_lds[ns * 16 + rn][k * 32 + kq * 8];
      acc = mfma16(af, bf, acc);
    }
    int ng = n0 + ns * 16 + rn;
    if (ng < N_) {
#pragma unroll
      for (int r = 0; r < 4; ++r) {
        int row = rowbase + rt * 16 + kq * 4 + r;
        out[((size_t)b * A_ + row) * N_ + ng] = acc[r] * norm2;
      }
    }
  }
}

// ---------------- row softmax ----------------
__global__ __launch_bounds__(256) void k_softmax(float* __restrict__ out,
                                                 const unsigned char* __restrict__ mask,
                                                 const int* __restrict__ Tptr) {
  __shared__ float z[N_];
  __shared__ float red[4];
  const size_t row = blockIdx.x;
  const int tid = threadIdx.x;
  const float Tinv = 1.0f / (float)Tptr[0];

  float lmax = -3.0e38f;
  for (int i = tid; i < N_; i += 256) {
    float v = out[row * N_ + i];
    if (mask[row * N_ + i]) v = -1e4f;
    v *= Tinv;
    z[i] = v;
    lmax = fmaxf(lmax, v);
  }
#pragma unroll
  for (int off = 1; off < 64; off <<= 1) lmax = fmaxf(lmax, __shfl_xor(lmax, off));
  if ((tid & 63) == 0) red[tid >> 6] = lmax;
  __syncthreads();
  float gmax = fmaxf(fmaxf(red[0], red[1]), fmaxf(red[2], red[3]));

  float lsum = 0.f;
  for (int i = tid; i < N_; i += 256) {
    float e = __expf(z[i] - gmax);
    z[i] = e;
    lsum += e;
  }
#pragma unroll
  for (int off = 1; off < 64; off <<= 1) lsum += __shfl_xor(lsum, off);
  __syncthreads();
  if ((tid & 63) == 0) red[tid >> 6] = lsum;
  __syncthreads();
  float inv = 1.0f / (red[0] + red[1] + red[2] + red[3]);
  for (int i = tid; i < N_; i += 256) out[row * N_ + i] = z[i] * inv;
}

// ---------------- launch ----------------
extern "C" void kernel_launch(void* const* d_in, const int* in_sizes, int n_in,
                              void* d_out, int out_size, void* d_ws, size_t ws_size,
                              hipStream_t stream) {
  const float* state_t   = (const float*)d_in[0];
  const float* context   = (const float*)d_in[1];
  const float* context_d = (const float*)d_in[2];
  const float* w_q  = (const float*)d_in[3];
  const float* w_k1 = (const float*)d_in[4];
  const float* w_v1 = (const float*)d_in[5];
  const float* w_fc = (const float*)d_in[6];
  const float* w_k2 = (const float*)d_in[7];
  const int* maski  = (const int*)d_in[9];
  const int* Tptr   = (const int*)d_in[10];
  float* out = (float*)d_out;

  char* ws = (char*)d_ws;
  unsigned short* ctxb  = (unsigned short*)ws; ws += (size_t)B_ * N_ * DIN * 2;
  unsigned short* ctxdb = (unsigned short*)ws; ws += (size_t)B_ * N_ * DIN * 2;
  unsigned short* stb   = (unsigned short*)ws; ws += (size_t)B_ * A_ * DIN * 2;
  unsigned short* wqb   = (unsigned short*)ws; ws += (size_t)HID * DIN * 2;
  unsigned short* wk1b  = (unsigned short*)ws; ws += (size_t)HID * DIN * 2;
  unsigned short* wv1b  = (unsigned short*)ws; ws += (size_t)HID * DIN * 2;
  unsigned short* wk2b  = (unsigned short*)ws; ws += (size_t)HID * DIN * 2;
  unsigned short* wfcb  = (unsigned short*)ws; ws += (size_t)HID * HID * 2;
  unsigned char*  mask8 = (unsigned char*)ws;  ws += (size_t)B_ * A_ * N_;
  float*          x     = (float*)ws;          ws += (size_t)B_ * A_ * HID * 4;
  unsigned short* x2    = (unsigned short*)ws; ws += (size_t)B_ * A_ * HID * 2;

  k_cvt<<<2048, 256, 0, stream>>>(context,   ctxb,  B_ * N_ * DIN / 4);
  k_cvt<<<2048, 256, 0, stream>>>(context_d, ctxdb, B_ * N_ * DIN / 4);
  k_cvt<<<256,  256, 0, stream>>>(state_t,   stb,   B_ * A_ * DIN / 4);
  k_cvt<<<64,   256, 0, stream>>>(w_q,  wqb,  HID * DIN / 4);
  k_cvt<<<64,   256, 0, stream>>>(w_k1, wk1b, HID * DIN / 4);
  k_cvt<<<64,   256, 0, stream>>>(w_v1, wv1b, HID * DIN / 4);
  k_cvt<<<64,   256, 0, stream>>>(w_k2, wk2b, HID * DIN / 4);
  k_cvt<<<256,  256, 0, stream>>>(w_fc, wfcb, HID * HID / 4);
  k_mask<<<2048, 256, 0, stream>>>(maski, mask8, B_ * A_ * N_ / 4);

  k_attn1<<<2048, 256, 0, stream>>>(stb, ctxb, ctxdb, wqb, wk1b, wv1b, mask8, x);

  k_fc<<<(B_ * A_) / 16, 256, 0, stream>>>(x, wfcb, x2);

  dim3 g3((N_ + 31) / 32, 2, B_);
  k_logits<<<g3, 256, 0, stream>>>(ctxb, ctxdb, wk2b, x2, out);

  k_softmax<<<B_ * A_, 256, 0, stream>>>(out, mask8, Tptr);
}

// Round 3
// 486.461 us; speedup vs baseline: 2.6196x; 1.6131x over previous
//
#include <hip/hip_runtime.h>

typedef short s16x8 __attribute__((ext_vector_type(8)));
typedef float f32x4 __attribute__((ext_vector_type(4)));

#define B_   128
#define A_   64
#define N_   2000
#define DIN  128
#define HID  512
#define H_   8
#define HD_  64
#define ND_  16
#define NT_  32

__device__ __forceinline__ unsigned short f2bf(float f) {
  union { float f; unsigned int u; } v; v.f = f;
  unsigned int u = v.u;
  unsigned int r = (u + 0x7fffu + ((u >> 16) & 1u)) >> 16;
  return (unsigned short)r;
}

__device__ __forceinline__ float bf2f(unsigned int u16v) {
  union { unsigned int u; float f; } v; v.u = u16v << 16;
  return v.f;
}

__device__ __forceinline__ f32x4 mfma16(s16x8 a, s16x8 b, f32x4 c) {
  return __builtin_amdgcn_mfma_f32_16x16x32_bf16(a, b, c, 0, 0, 0);
}

__device__ __forceinline__ unsigned int cvtpk(float lo, float hi) {
  unsigned int r;
  asm("v_cvt_pk_bf16_f32 %0, %1, %2" : "=v"(r) : "v"(lo), "v"(hi));
  return r;
}

__device__ __forceinline__ void gload16(const void* g, void* l) {
  __builtin_amdgcn_global_load_lds(
      (const __attribute__((address_space(1))) unsigned int*)g,
      (__attribute__((address_space(3))) unsigned int*)l, 16, 0, 0);
}

__device__ __forceinline__ void barrier_lds() {
  asm volatile("s_waitcnt lgkmcnt(0)" ::: "memory");
  __builtin_amdgcn_s_barrier();
  __builtin_amdgcn_sched_barrier(0);
}
__device__ __forceinline__ void barrier_full() {
  asm volatile("s_waitcnt vmcnt(0) lgkmcnt(0)" ::: "memory");
  __builtin_amdgcn_s_barrier();
  __builtin_amdgcn_sched_barrier(0);
}

// ---------------- converts ----------------
__global__ __launch_bounds__(256) void k_cvt(const float* __restrict__ src,
                                             unsigned short* __restrict__ dst, int n4) {
  int i = blockIdx.x * blockDim.x + threadIdx.x;
  int stride = gridDim.x * blockDim.x;
  for (; i < n4; i += stride) {
    float4 v = ((const float4*)src)[i];
    ushort4 o;
    o.x = f2bf(v.x); o.y = f2bf(v.y); o.z = f2bf(v.z); o.w = f2bf(v.w);
    ((ushort4*)dst)[i] = o;
  }
}

// wk2 (512x128 f32) -> wk2t (128x512 bf16)
__global__ __launch_bounds__(256) void k_cvt_t(const float* __restrict__ src,
                                               unsigned short* __restrict__ dst) {
  int i = blockIdx.x * 256 + threadIdx.x;   // 0..65535
  int o = i >> 7, d = i & 127;
  dst[d * 512 + o] = f2bf(src[i]);
}

__global__ __launch_bounds__(256) void k_mask(const int* __restrict__ src,
                                              unsigned char* __restrict__ dst, int n4) {
  int i = blockIdx.x * blockDim.x + threadIdx.x;
  int stride = gridDim.x * blockDim.x;
  for (; i < n4; i += stride) {
    int4 v = ((const int4*)src)[i];
    uchar4 o;
    o.x = v.x ? 1 : 0; o.y = v.y ? 1 : 0; o.z = v.z ? 1 : 0; o.w = v.w ? 1 : 0;
    ((uchar4*)dst)[i] = o;
  }
}

// ---------------- fused attn1 (flash over N, fixed-max softmax) ----------------
template <int BR>
__device__ __forceinline__ void attn_body(
    int sub,
    const unsigned short* __restrict__ st, const unsigned short* __restrict__ C,
    const unsigned short* __restrict__ wq, const unsigned short* __restrict__ wk1,
    const unsigned short* __restrict__ wv1, const unsigned char* __restrict__ mask,
    float* __restrict__ x,
    unsigned short (*ctx_lds)[128], unsigned short (*K_lds)[72],
    unsigned short (*VT_lds)[72], unsigned short (*QP_lds)[72], float (*red_l)[48]) {
  constexpr int AT = BR ? 3 : 1;
  constexpr int a0 = BR ? ND_ : 0;
  const int tid = threadIdx.x;
  const int w = tid >> 6, lane = tid & 63, rn = lane & 15, kq = lane >> 4;
  const int b = sub >> 3, h = sub & 7;
  const int srow = lane >> 4;
  const int scol = lane & 15;

#pragma unroll
  for (int i = 0; i < 4; ++i) {
    int r0 = i * 16 + w * 4;
    int row = r0 + srow;
    const char* g = (const char*)C + (((size_t)b * N_ + row) << 8) + ((scol ^ (row & 7)) << 4);
    gload16(g, (char*)&ctx_lds[0][0] + (r0 << 8));
  }

  s16x8 kfrag[4], vfrag[4];
  {
    const size_t orow = (size_t)(h * HD_ + w * 16 + rn) * DIN;
#pragma unroll
    for (int k = 0; k < 4; ++k) {
      kfrag[k] = *(const s16x8*)(wk1 + orow + k * 32 + kq * 8);
      vfrag[k] = *(const s16x8*)(wv1 + orow + k * 32 + kq * 8);
    }
  }

  {
    s16x8 qw[4];
    const size_t orow = (size_t)(h * HD_ + w * 16 + rn) * DIN;
#pragma unroll
    for (int k = 0; k < 4; ++k) qw[k] = *(const s16x8*)(wq + orow + k * 32 + kq * 8);
#pragma unroll
    for (int at = 0; at < AT; ++at) {
      f32x4 acc = {0.f, 0.f, 0.f, 0.f};
#pragma unroll
      for (int k = 0; k < 4; ++k) {
        s16x8 sf = *(const s16x8*)(st + (size_t)(b * A_ + a0 + at * 16 + rn) * DIN + k * 32 + kq * 8);
        acc = mfma16(qw[k], sf, acc);
      }
      uint2 pk; pk.x = cvtpk(acc[0], acc[1]); pk.y = cvtpk(acc[2], acc[3]);
      *(uint2*)&QP_lds[at * 16 + rn][w * 16 + kq * 4] = pk;
    }
  }
  barrier_lds();

  s16x8 qf[AT][2];
#pragma unroll
  for (int at = 0; at < AT; ++at)
#pragma unroll
    for (int kd = 0; kd < 2; ++kd)
      qf[at][kd] = *(const s16x8*)&QP_lds[at * 16 + rn][kd * 32 + kq * 8];

  f32x4 O[AT];
  float lpart[AT];
#pragma unroll
  for (int at = 0; at < AT; ++at) { O[at] = {0.f, 0.f, 0.f, 0.f}; lpart[at] = 0.f; }

  for (int nt = 0; nt < NT_; ++nt) {
    const int n0 = nt * 64;
    barrier_full();

    unsigned int m4[AT];
    const int ngbase = n0 + w * 16 + kq * 4;
    const int ngc = ngbase > (N_ - 4) ? (N_ - 4) : ngbase;
#pragma unroll
    for (int at = 0; at < AT; ++at)
      m4[at] = *(const unsigned int*)(mask + (size_t)(b * A_ + a0 + at * 16 + rn) * N_ + ngc);

#pragma unroll
    for (int ns = 0; ns < 4; ++ns) {
      s16x8 cf[4];
#pragma unroll
      for (int kd = 0; kd < 4; ++kd)
        cf[kd] = *(const s16x8*)&ctx_lds[ns * 16 + rn][(((kd << 2) | kq) ^ (rn & 7)) << 3];
      f32x4 aK = {0.f, 0.f, 0.f, 0.f}, aV = {0.f, 0.f, 0.f, 0.f};
#pragma unroll
      for (int kd = 0; kd < 4; ++kd) {
        aK = mfma16(kfrag[kd], cf[kd], aK);
        aV = mfma16(cf[kd], vfrag[kd], aV);
      }
      if (n0 + 64 > N_) {
#pragma unroll
        for (int r = 0; r < 4; ++r)
          if (n0 + ns * 16 + kq * 4 + r >= N_) aV[r] = 0.f;
      }
      uint2 pkK; pkK.x = cvtpk(aK[0], aK[1]); pkK.y = cvtpk(aK[2], aK[3]);
      *(uint2*)&K_lds[ns * 16 + rn][w * 16 + kq * 4] = pkK;
      uint2 pkV; pkV.x = cvtpk(aV[0], aV[1]); pkV.y = cvtpk(aV[2], aV[3]);
      *(uint2*)&VT_lds[w * 16 + rn][ns * 16 + kq * 4] = pkV;
    }
    barrier_lds();

    if (nt + 1 < NT_) {
      const int n1 = n0 + 64;
#pragma unroll
      for (int i = 0; i < 4; ++i) {
        int r0 = i * 16 + w * 4;
        int row = r0 + srow;
        const char* g = (const char*)C + (((size_t)b * N_ + n1 + row) << 8) + ((scol ^ (row & 7)) << 4);
        gload16(g, (char*)&ctx_lds[0][0] + (r0 << 8));
      }
    }

    s16x8 kf[2];
#pragma unroll
    for (int kd = 0; kd < 2; ++kd)
      kf[kd] = *(const s16x8*)&K_lds[w * 16 + rn][kd * 32 + kq * 8];
#pragma unroll
    for (int at = 0; at < AT; ++at) {
      f32x4 acc = {0.f, 0.f, 0.f, 0.f};
#pragma unroll
      for (int kd = 0; kd < 2; ++kd) acc = mfma16(kf[kd], qf[at][kd], acc);
      float p[4];
#pragma unroll
      for (int r = 0; r < 4; ++r) {
        bool valid = (ngbase + r < N_) && (((m4[at] >> (8 * r)) & 255u) == 0u);
        float e = valid ? acc[r] * 0.125f - 8.0f : -1.0e4f;
        p[r] = __expf(e);
      }
      lpart[at] += (p[0] + p[1]) + (p[2] + p[3]);
      uint2 pkP; pkP.x = cvtpk(p[0], p[1]); pkP.y = cvtpk(p[2], p[3]);
      *(uint2*)&QP_lds[at * 16 + rn][w * 16 + kq * 4] = pkP;
    }
    barrier_lds();

    s16x8 vtf[2];
#pragma unroll
    for (int kn = 0; kn < 2; ++kn)
      vtf[kn] = *(const s16x8*)&VT_lds[w * 16 + rn][kn * 32 + kq * 8];
#pragma unroll
    for (int at = 0; at < AT; ++at) {
      f32x4 acc = O[at];
#pragma unroll
      for (int kn = 0; kn < 2; ++kn)
        acc = mfma16(*(const s16x8*)&QP_lds[at * 16 + rn][kn * 32 + kq * 8], vtf[kn], acc);
      O[at] = acc;
    }
  }

#pragma unroll
  for (int at = 0; at < AT; ++at) {
    float lp = lpart[at];
    lp += __shfl_xor(lp, 16);
    lp += __shfl_xor(lp, 32);
    if (kq == 0) red_l[w][at * 16 + rn] = lp;
  }
  barrier_lds();
#pragma unroll
  for (int at = 0; at < AT; ++at) {
#pragma unroll
    for (int r = 0; r < 4; ++r) {
      int a = at * 16 + kq * 4 + r;
      float ls = (red_l[0][a] + red_l[1][a]) + (red_l[2][a] + red_l[3][a]);
      float val = O[at][r] / ls;
      int row = BR ? (ND_ + h * 6 + (a >> 3)) : (h * 2 + (a >> 3));
      int col = (a & 7) * HD_ + w * 16 + rn;
      x[((size_t)b * A_ + row) * HID + col] = val;
    }
  }
}

__global__ __launch_bounds__(256) void k_attn1(const unsigned short* __restrict__ st,
                                               const unsigned short* __restrict__ ctx,
                                               const unsigned short* __restrict__ ctxd,
                                               const unsigned short* __restrict__ wq,
                                               const unsigned short* __restrict__ wk1,
                                               const unsigned short* __restrict__ wv1,
                                               const unsigned char* __restrict__ mask,
                                               float* __restrict__ x) {
  __shared__ unsigned short ctx_lds[64][128];
  __shared__ unsigned short K_lds[64][72];
  __shared__ unsigned short VT_lds[64][72];
  __shared__ unsigned short QP_lds[48][72];
  __shared__ float red_l[4][48];
  const int bid = blockIdx.x;
  const int sub = bid >> 1;
  if (bid & 1)
    attn_body<1>(sub, st, ctx, wq, wk1, wv1, mask, x, ctx_lds, K_lds, VT_lds, QP_lds, red_l);
  else
    attn_body<0>(sub, st, ctxd, wq, wk1, wv1, mask, x, ctx_lds, K_lds, VT_lds, QP_lds, red_l);
}

// ---------------- fused fc + y2: y2 = norm2 * ((x @ wfc^T) @ wk2) ----------------
__global__ __launch_bounds__(256) void k_fc2(const float* __restrict__ x,
                                             const unsigned short* __restrict__ wfc,
                                             const unsigned short* __restrict__ wk2t,
                                             unsigned short* __restrict__ y2b) {
  __shared__ unsigned short x2_lds[16][520];
  const int tid = threadIdx.x;
  const int w = tid >> 6;
  const int lane = tid & 63;
  const int rn = lane & 15, kq = lane >> 4;
  const size_t rowbase = (size_t)blockIdx.x * 16;
  const float norm2 = 0.04419417382415922f;   // 1/sqrt(512)

  f32x4 acc[8];
#pragma unroll
  for (int ot = 0; ot < 8; ++ot) acc[ot] = {0.f, 0.f, 0.f, 0.f};

  for (int k = 0; k < 16; ++k) {
    const float* ap = x + (rowbase + rn) * HID + k * 32 + kq * 8;
    float4 a1 = *(const float4*)ap;
    float4 a2 = *(const float4*)(ap + 4);
    s16x8 af;
    af[0] = (short)f2bf(a1.x); af[1] = (short)f2bf(a1.y);
    af[2] = (short)f2bf(a1.z); af[3] = (short)f2bf(a1.w);
    af[4] = (short)f2bf(a2.x); af[5] = (short)f2bf(a2.y);
    af[6] = (short)f2bf(a2.z); af[7] = (short)f2bf(a2.w);
#pragma unroll
    for (int ot = 0; ot < 8; ++ot) {
      s16x8 bf = *(const s16x8*)(wfc + (size_t)(w * 128 + ot * 16 + rn) * HID + k * 32 + kq * 8);
      acc[ot] = mfma16(af, bf, acc[ot]);
    }
  }
#pragma unroll
  for (int ot = 0; ot < 8; ++ot)
#pragma unroll
    for (int r = 0; r < 4; ++r)
      x2_lds[kq * 4 + r][w * 128 + ot * 16 + rn] = f2bf(acc[ot][r]);
  __syncthreads();

  // y2 = x2 @ wk2  (K = 512), wave w covers out cols [w*32, w*32+32)
#pragma unroll
  for (int j = 0; j < 2; ++j) {
    const int d0 = w * 32 + j * 16;
    f32x4 acc2 = {0.f, 0.f, 0.f, 0.f};
    for (int kk = 0; kk < 16; ++kk) {
      s16x8 af2 = *(const s16x8*)&x2_lds[rn][kk * 32 + kq * 8];
      s16x8 bf2 = *(const s16x8*)(wk2t + (size_t)(d0 + rn) * HID + kk * 32 + kq * 8);
      acc2 = mfma16(af2, bf2, acc2);
    }
#pragma unroll
    for (int r = 0; r < 4; ++r)
      y2b[(rowbase + kq * 4 + r) * DIN + d0 + rn] = f2bf(acc2[r] * norm2);
  }
}

// ---------------- fused logits + softmax ----------------
// block = (a-tile of 16, b). P tile (16 x 2048 bf16) lives in LDS; fixed-max exp.
__global__ __launch_bounds__(256) void k_logits_sm(const unsigned short* __restrict__ ctx,
                                                   const unsigned short* __restrict__ ctxd,
                                                   const unsigned short* __restrict__ y2b,
                                                   const unsigned char* __restrict__ mask,
                                                   const int* __restrict__ Tptr,
                                                   float* __restrict__ out) {
  __shared__ unsigned short ctx_lds[3][64][128];
  __shared__ unsigned short p_lds[16][2048];
  __shared__ float red_l[4][16];

  const int tid = threadIdx.x;
  const int w = tid >> 6, lane = tid & 63, rn = lane & 15, kq = lane >> 4;
  const int atile = blockIdx.x;           // 0..3
  const int b = blockIdx.y;
  const int a0 = atile * 16;
  const unsigned short* __restrict__ C = atile ? ctx : ctxd;
  const float Tinv = 1.0f / (float)Tptr[0];
  const int srow = lane >> 4, scol = lane & 15;
  const size_t bN = (size_t)b * N_;
  const size_t mrow = (size_t)(b * A_ + a0 + rn) * N_;

  // y2 B-fragments (row a = a0+rn)
  s16x8 yf[4];
#pragma unroll
  for (int kd = 0; kd < 4; ++kd)
    yf[kd] = *(const s16x8*)(y2b + (size_t)(b * A_ + a0 + rn) * DIN + kd * 32 + kq * 8);

  // prologue: mask for tile 0, stage tiles 0 and 1
  unsigned int mcur = *(const unsigned int*)(mask + mrow + w * 16 + kq * 4);
#pragma unroll
  for (int i = 0; i < 4; ++i) {
    int r0 = i * 16 + w * 4;
    int row = r0 + srow;
    gload16((const char*)C + ((bN + row) << 8) + ((scol ^ (row & 7)) << 4),
            (char*)&ctx_lds[0][0][0] + (r0 << 8));
  }
#pragma unroll
  for (int i = 0; i < 4; ++i) {
    int r0 = i * 16 + w * 4;
    int row = r0 + srow;
    gload16((const char*)C + ((bN + 64 + row) << 8) + ((scol ^ (row & 7)) << 4),
            (char*)&ctx_lds[1][0][0] + (r0 << 8));
  }

  float lpart = 0.f;
  for (int nt = 0; nt < NT_; ++nt) {
    const int n0 = nt * 64;
    if (nt == 0) { asm volatile("s_waitcnt vmcnt(4)" ::: "memory"); }
    else         { asm volatile("s_waitcnt vmcnt(5)" ::: "memory"); }
    __builtin_amdgcn_s_barrier();
    __builtin_amdgcn_sched_barrier(0);

    // prefetch mask (tile nt+1) and stage (tile nt+2)
    unsigned int mnext;
    {
      int nb1 = (nt + 1 < NT_ ? nt + 1 : 0) * 64 + w * 16 + kq * 4;
      int ngc = nb1 > (N_ - 4) ? (N_ - 4) : nb1;
      mnext = *(const unsigned int*)(mask + mrow + ngc);
    }
    {
      int t2 = nt + 2 < NT_ ? nt + 2 : 0;
      char* dstb = (char*)&ctx_lds[(nt + 2) % 3][0][0];
#pragma unroll
      for (int i = 0; i < 4; ++i) {
        int r0 = i * 16 + w * 4;
        int row = r0 + srow;
        gload16((const char*)C + ((bN + t2 * 64 + row) << 8) + ((scol ^ (row & 7)) << 4),
                dstb + (r0 << 8));
      }
    }

    // compute tile nt
    const unsigned short (*buf)[128] = ctx_lds[nt % 3];
    f32x4 acc = {0.f, 0.f, 0.f, 0.f};
#pragma unroll
    for (int kd = 0; kd < 4; ++kd) {
      s16x8 cf = *(const s16x8*)&buf[w * 16 + rn][(((kd << 2) | kq) ^ (rn & 7)) << 3];
      acc = mfma16(cf, yf[kd], acc);
    }
    const int nbase = n0 + w * 16 + kq * 4;
    float pv[4];
#pragma unroll
    for (int r = 0; r < 4; ++r) {
      bool valid = (nbase + r < N_) && (((mcur >> (8 * r)) & 255u) == 0u);
      pv[r] = valid ? __expf(acc[r] * Tinv - 8.0f) : 0.f;
    }
    lpart += (pv[0] + pv[1]) + (pv[2] + pv[3]);
    uint2 pk; pk.x = cvtpk(pv[0], pv[1]); pk.y = cvtpk(pv[2], pv[3]);
    int bo = (rn << 12) + (nbase << 1);
    *(uint2*)((char*)p_lds + (bo ^ ((rn & 7) << 4))) = pk;
    mcur = mnext;
  }

  // reduce l per a-row
  float lp = lpart;
  lp += __shfl_xor(lp, 16);
  lp += __shfl_xor(lp, 32);
  if (kq == 0) red_l[w][rn] = lp;
  barrier_full();

  // stream normalized rows to out
  const size_t outbase = ((size_t)b * A_ + a0) * (size_t)N_;
  for (int row = 0; row < 16; ++row) {
    float l = (red_l[0][row] + red_l[1][row]) + (red_l[2][row] + red_l[3][row]);
    float inv = 1.0f / l;
    if (tid < 250) {
      const char* srcp = (const char*)p_lds + (row << 12) + ((tid ^ (row & 7)) << 4);
      uint2 pk = *(const uint2*)srcp;
      float4 o0, o1;
      o0.x = bf2f(pk.x & 0xFFFFu) * inv;
      o0.y = bf2f(pk.x >> 16) * inv;
      o0.z = bf2f(pk.y & 0xFFFFu) * inv;
      o0.w = bf2f(pk.y >> 16) * inv;
      const char* srcp2 = srcp + 8;
      uint2 pk2 = *(const uint2*)srcp2;
      o1.x = bf2f(pk2.x & 0xFFFFu) * inv;
      o1.y = bf2f(pk2.x >> 16) * inv;
      o1.z = bf2f(pk2.y & 0xFFFFu) * inv;
      o1.w = bf2f(pk2.y >> 16) * inv;
      float* op = out + outbase + (size_t)row * N_ + tid * 8;
      *(float4*)op = o0;
      *(float4*)(op + 4) = o1;
    }
  }
}

// ---------------- launch ----------------
extern "C" void kernel_launch(void* const* d_in, const int* in_sizes, int n_in,
                              void* d_out, int out_size, void* d_ws, size_t ws_size,
                              hipStream_t stream) {
  const float* state_t   = (const float*)d_in[0];
  const float* context   = (const float*)d_in[1];
  const float* context_d = (const float*)d_in[2];
  const float* w_q  = (const float*)d_in[3];
  const float* w_k1 = (const float*)d_in[4];
  const float* w_v1 = (const float*)d_in[5];
  const float* w_fc = (const float*)d_in[6];
  const float* w_k2 = (const float*)d_in[7];
  const int* maski  = (const int*)d_in[9];
  const int* Tptr   = (const int*)d_in[10];
  float* out = (float*)d_out;

  char* ws = (char*)d_ws;
  unsigned short* ctxb  = (unsigned short*)ws; ws += (size_t)B_ * N_ * DIN * 2;
  unsigned short* ctxdb = (unsigned short*)ws; ws += (size_t)B_ * N_ * DIN * 2;
  unsigned short* stb   = (unsigned short*)ws; ws += (size_t)B_ * A_ * DIN * 2;
  unsigned short* wqb   = (unsigned short*)ws; ws += (size_t)HID * DIN * 2;
  unsigned short* wk1b  = (unsigned short*)ws; ws += (size_t)HID * DIN * 2;
  unsigned short* wv1b  = (unsigned short*)ws; ws += (size_t)HID * DIN * 2;
  unsigned short* wk2t  = (unsigned short*)ws; ws += (size_t)HID * DIN * 2;
  unsigned short* wfcb  = (unsigned short*)ws; ws += (size_t)HID * HID * 2;
  unsigned char*  mask8 = (unsigned char*)ws;  ws += (size_t)B_ * A_ * N_;
  float*          x     = (float*)ws;          ws += (size_t)B_ * A_ * HID * 4;
  unsigned short* y2b   = (unsigned short*)ws; ws += (size_t)B_ * A_ * DIN * 2;

  k_cvt<<<2048, 256, 0, stream>>>(context,   ctxb,  B_ * N_ * DIN / 4);
  k_cvt<<<2048, 256, 0, stream>>>(context_d, ctxdb, B_ * N_ * DIN / 4);
  k_cvt<<<256,  256, 0, stream>>>(state_t,   stb,   B_ * A_ * DIN / 4);
  k_cvt<<<64,   256, 0, stream>>>(w_q,  wqb,  HID * DIN / 4);
  k_cvt<<<64,   256, 0, stream>>>(w_k1, wk1b, HID * DIN / 4);
  k_cvt<<<64,   256, 0, stream>>>(w_v1, wv1b, HID * DIN / 4);
  k_cvt_t<<<256, 256, 0, stream>>>(w_k2, wk2t);
  k_cvt<<<256,  256, 0, stream>>>(w_fc, wfcb, HID * HID / 4);
  k_mask<<<2048, 256, 0, stream>>>(maski, mask8, B_ * A_ * N_ / 4);

  k_attn1<<<2048, 256, 0, stream>>>(stb, ctxb, ctxdb, wqb, wk1b, wv1b, mask8, x);

  k_fc2<<<(B_ * A_) / 16, 256, 0, stream>>>(x, wfcb, wk2t, y2b);

  dim3 gl(4, B_);
  k_logits_sm<<<gl, 256, 0, stream>>>(ctxb, ctxdb, y2b, mask8, Tptr, out);
}